// Round 9
// baseline (62.529 us; speedup 1.0000x reference)
//
#include <hip/hip_runtime.h>
#include <stdint.h>

#define HH 64
#define WW 64
#define PIN 64
#define POUT 64
#define NFEAT 54

typedef _Float16 half8 __attribute__((ext_vector_type(8)));
typedef _Float16 half4 __attribute__((ext_vector_type(4)));
typedef float f32x4 __attribute__((ext_vector_type(4)));
typedef float f32x16 __attribute__((ext_vector_type(16)));

// feature enumeration tables: f -> (k,l), matching prep_filters order
__constant__ const int KT[54] = {0,0,0,0,0,0,0,0,0, 1,1,1,1,1,1,1,1,1, 2,2,2,2,2,2,2,2,
                                 3,3,3,3,3,3,3, 4,4,4,4,4,4, 5,5,5,5,5, 6,6,6,6, 7,7,7, 8,8, 9};
__constant__ const int LT[54] = {1,2,3,4,5,6,7,8,9, 1,2,3,4,5,6,7,8,9, 2,3,4,5,6,7,8,9,
                                 3,4,5,6,7,8,9, 4,5,6,7,8,9, 5,6,7,8,9, 6,7,8,9, 7,8,9, 8,9, 9};

// ---------------- filter prep ----------------
// Fprep[f][o][c] fp16; Fconst[o] = bias + sum_c F[o,c,0,0]. 8 parts per feature.
__global__ void prep_filters(const float* __restrict__ f, const float* __restrict__ bias,
                             _Float16* __restrict__ fprep, float* __restrict__ fconst) {
    int blk = blockIdx.x;
    if (blk == NFEAT * 8) {
        int o = threadIdx.x;
        if (o < POUT) {
            float s = bias[o];
            for (int c = 0; c < PIN; ++c) s += f[(size_t)(o * PIN + c) * 100];
            fconst[o] = s;
        }
        return;
    }
    int feat = blk >> 3, part = blk & 7;
    int k = 0, l = 0, cnt = 0;
    for (int kk = 0; kk <= 9; ++kk) {
        int ls = (kk == 0) ? 1 : kk;
        for (int ll = ls; ll <= 9; ++ll) {
            if (cnt == feat) { k = kk; l = ll; }
            ++cnt;
        }
    }
    int iend = (part + 1) * 512;
    for (int i = part * 512 + threadIdx.x; i < iend; i += 256) {
        int o = i >> 6, c = i & 63;
        const float* fc = f + (size_t)(o * PIN + c) * 100;
        float v;
        if (k == 0)      v = fc[l] + fc[l * 10];
        else if (k == l) v = fc[k * 10 + k];
        else             v = fc[k * 10 + l] + fc[l * 10 + k];
        fprep[((size_t)feat * POUT + o) * PIN + c] = (_Float16)v;
    }
}

// ---------------- main MFMA kernel ----------------
// grid 512 = b(8) x hrow(64), XCD-swizzled; block 512 thr = 8 waves =
// 2 m-tiles (32 px) x 4 kc-quarters (K=16). MFMA 32x32x16_f16.
// Barrier-free main loop: each wave streams its B fragments from global
// (L1/L2-resident Fprep) through a depth-4 register ring. No LDS B ring.
// LDS only: x tile (25.3KB), reused for the fp32 kc-reduction epilogue.
__global__ __launch_bounds__(512, 4) void poly2d_mfma(
    const float* __restrict__ x, const _Float16* __restrict__ fprep,
    const float* __restrict__ fconst, float* __restrict__ out)
{
    __shared__ __align__(16) char smx[25344];  // x tile [3][66][8cg swz][16B]; reused as os[64][65] f32

    const int t = threadIdx.x;
    const int lane = t & 63;
    const int wid = t >> 6;            // 0..7
    // XCD-bijective swizzle (512 % 8 == 0): each XCD gets 64 consecutive rows of one batch
    const int bid = (blockIdx.x & 7) * 64 + (blockIdx.x >> 3);
    const int b = bid >> 6;
    const int hrow = bid & 63;

    // ---- stage x tile (rows hrow-1..hrow+1, wl 0..65, 64 c) as swizzled fp16 ----
    {
        const int w = t & 63;
        const int wl = w + 1;
        #pragma unroll
        for (int h = 0; h < 3; ++h) {
            int h_in = hrow - 1 + h;
            bool hok = ((unsigned)h_in < HH);
            #pragma unroll
            for (int cc = 0; cc < 2; ++cc) {
                int c = wid * 8 + cc * 4;  // channels c..c+3
                float v0 = 0.f, v1 = 0.f, v2 = 0.f, v3 = 0.f;
                if (hok) {
                    const float* gx = x + (((size_t)b * PIN + c) * HH + h_in) * WW + w;
                    v0 = gx[0]; v1 = gx[4096]; v2 = gx[8192]; v3 = gx[12288];
                }
                half4 pk = {(_Float16)v0, (_Float16)v1, (_Float16)v2, (_Float16)v3};
                int byte = ((h * 66 + wl) * 8 + ((c >> 3) ^ (wl & 7))) * 16 + (c & 7) * 2;
                *(half4*)(smx + byte) = pk;
            }
        }
        if (t < 48) { // w halo: wl=0 and wl=65 out of image -> zero. 3 rows x 2 sides x 8 cg
            int h = t >> 4, side = (t >> 3) & 1, cg = t & 7;
            int wl2 = side ? 65 : 0;
            int byte = ((h * 66 + wl2) * 8 + (cg ^ (wl2 & 7))) * 16;
            f32x4 z = {0.f, 0.f, 0.f, 0.f};
            *(f32x4*)(smx + byte) = z;
        }
    }
    __syncthreads();

    const int kc = wid >> 1;           // 0..3 channel quarter
    const int mwid = wid & 1;          // m-tile (w-half)
    const int wbase = mwid * 32;
    const int l31 = lane & 31;
    const int lhi = lane >> 5;         // 0/1

    // ---- load 9 shift panels (A-frag: row=lane&31 -> pixel, k=(lane>>5)*8+j) ----
    half8 xp[9];
    #pragma unroll
    for (int p = 1; p <= 9; ++p) {
        const int dh = (p - 1) / 3 - 1, dw = (p - 1) % 3 - 1;
        int wl = wbase + l31 + dw + 1;
        int hidx = dh + 1;
        int cgl = kc * 2 + lhi;
        int byte = ((hidx * 66 + wl) * 8 + (cgl ^ (wl & 7))) * 16;
        xp[p - 1] = *(const half8*)(smx + byte);
    }
    __syncthreads(); // all xp reads done before anyone can reach the os-write epilogue

    // ---- barrier-free streaming loop: B frags direct from global, depth-4 reg ring ----
    // b0: o=l31,    bytes f*8192 + o*128 + kc*32 + lhi*16
    // b1: o=l31+32, +4096
    const char* fbase = (const char*)fprep + l31 * 128 + kc * 32 + lhi * 16;

    half8 Bb[4][2];
    #pragma unroll
    for (int s = 0; s < 3; ++s) {
        Bb[s][0] = *(const half8*)(fbase + (size_t)s * 8192);
        Bb[s][1] = *(const half8*)(fbase + (size_t)s * 8192 + 4096);
    }

    f32x16 acc0 = {}, acc1 = {};

    #pragma unroll
    for (int f = 0; f < NFEAT; ++f) {
        if (f + 3 < NFEAT) {
            Bb[(f + 3) & 3][0] = *(const half8*)(fbase + (size_t)(f + 3) * 8192);
            Bb[(f + 3) & 3][1] = *(const half8*)(fbase + (size_t)(f + 3) * 8192 + 4096);
        }
        const int k = KT[f], l = LT[f];
        half8 a = (k == 0) ? xp[l - 1] : xp[k - 1] * xp[l - 1];
        acc0 = __builtin_amdgcn_mfma_f32_32x32x16_f16(a, Bb[f & 3][0], acc0, 0, 0, 0);
        acc1 = __builtin_amdgcn_mfma_f32_32x32x16_f16(a, Bb[f & 3][1], acc1, 0, 0, 0);
    }

    __syncthreads(); // loop done; x-region free for output staging
    float* os = (float*)smx; // [64 px][65]

    // reduce 4 kc partials (C/D: col=lane&31 (+nb*32), row=(r&3)+8*(r>>2)+4*lhi)
    #pragma unroll
    for (int pass = 0; pass < 4; ++pass) {
        if (kc == pass) {
            #pragma unroll
            for (int nb = 0; nb < 2; ++nb) {
                #pragma unroll
                for (int r = 0; r < 16; ++r) {
                    int row = (r & 3) + 8 * (r >> 2) + 4 * lhi;
                    int m = mwid * 32 + row;
                    int col = l31 + nb * 32;
                    float v = nb ? acc1[r] : acc0[r];
                    if (pass == 0) os[m * 65 + col] = v;
                    else           os[m * 65 + col] += v;
                }
            }
        }
        __syncthreads();
    }

    { // coalesced store: lanes sweep w
        const int w = t & 63;
        #pragma unroll
        for (int oo = 0; oo < 8; ++oo) {
            int o = wid * 8 + oo;
            float val = os[w * 65 + o] + fconst[o];
            out[(((size_t)b * POUT + o) * HH + hrow) * WW + w] = val;
        }
    }
}

// ---------------- fp32 fallback, used only if ws too small ----------------
__global__ __launch_bounds__(256) void poly2d_fp32(
    const float* __restrict__ x, const float* __restrict__ f,
    const float* __restrict__ bias, float* __restrict__ out)
{
    const int t = threadIdx.x;
    const int wo = t & 63;
    const int ho = (blockIdx.x & 15) * 4 + (t >> 6);
    const int o = (blockIdx.x >> 4) & 63;
    const int b = blockIdx.x >> 10;

    float acc = bias[o];
    const float* xb = x + (size_t)b * PIN * HH * WW;
    const float* fo = f + (size_t)o * PIN * 100;
    for (int c = 0; c < PIN; ++c) {
        const float* xc = xb + (size_t)c * HH * WW;
        float s[10];
        s[0] = 1.0f;
        #pragma unroll
        for (int kh = 0; kh < 3; ++kh) {
            int h = ho - 1 + kh;
            bool hok = ((unsigned)h < HH);
            #pragma unroll
            for (int kw = 0; kw < 3; ++kw) {
                int w = wo - 1 + kw;
                s[1 + kh * 3 + kw] = (hok && (unsigned)w < WW) ? xc[h * WW + w] : 0.0f;
            }
        }
        const float* fc = fo + c * 100;
        #pragma unroll
        for (int i = 0; i < 10; ++i) {
            float wsum = 0.0f;
            #pragma unroll
            for (int j = 0; j < 10; ++j) wsum = fmaf(fc[i * 10 + j], s[j], wsum);
            acc = fmaf(wsum, s[i], acc);
        }
    }
    out[(((size_t)b * POUT + o) * HH + ho) * WW + wo] = acc;
}

extern "C" void kernel_launch(void* const* d_in, const int* in_sizes, int n_in,
                              void* d_out, int out_size, void* d_ws, size_t ws_size,
                              hipStream_t stream) {
    const float* x    = (const float*)d_in[0];
    const float* filt = (const float*)d_in[1];
    const float* bias = (const float*)d_in[2];
    float* out = (float*)d_out;

    const size_t FPREP_BYTES = (size_t)NFEAT * POUT * PIN * 2; // 442368
    if (ws_size < FPREP_BYTES + 256) {
        poly2d_fp32<<<dim3(8 * 64 * 16), dim3(256), 0, stream>>>(x, filt, bias, out);
        return;
    }
    _Float16* fprep = (_Float16*)d_ws;
    float* fconst = (float*)((char*)d_ws + FPREP_BYTES);

    prep_filters<<<dim3(NFEAT * 8 + 1), dim3(256), 0, stream>>>(filt, bias, fprep, fconst);
    poly2d_mfma<<<dim3(512), dim3(512), 0, stream>>>(x, fprep, fconst, out);
}

// Round 10
// 29.690 us; speedup vs baseline: 2.1061x; 2.1061x over previous
//
#include <hip/hip_runtime.h>
#include <stdint.h>

#define HH 64
#define WW 64
#define PIN 64
#define POUT 64
#define NFEAT 54

typedef _Float16 half8 __attribute__((ext_vector_type(8)));
typedef _Float16 half4 __attribute__((ext_vector_type(4)));
typedef float f32x4 __attribute__((ext_vector_type(4)));
typedef float f32x16 __attribute__((ext_vector_type(16)));

// feature enumeration tables: f -> (k,l)
__constant__ const int KT[54] = {0,0,0,0,0,0,0,0,0, 1,1,1,1,1,1,1,1,1, 2,2,2,2,2,2,2,2,
                                 3,3,3,3,3,3,3, 4,4,4,4,4,4, 5,5,5,5,5, 6,6,6,6, 7,7,7, 8,8, 9};
__constant__ const int LT[54] = {1,2,3,4,5,6,7,8,9, 1,2,3,4,5,6,7,8,9, 2,3,4,5,6,7,8,9,
                                 3,4,5,6,7,8,9, 4,5,6,7,8,9, 5,6,7,8,9, 6,7,8,9, 7,8,9, 8,9, 9};

// ---------------- filter prep ----------------
// Writes Fprep in FRAGMENT order so the main loop's B loads are lane-contiguous:
//   byte(f,o,c) = f*8192 + (c>>4)*2048 + (o>>5)*1024 + ((o&31)+32*((c>>3)&1))*16 + (c&7)*2
// A wave (kc quarter) then reads b0 at f*8192+kc*2048+lane*16 (1KB contiguous), b1 at +1024.
// One thread produces one 16B chunk (fixed f,o, 8 consecutive c).
__global__ void prep_filters(const float* __restrict__ f, const float* __restrict__ bias,
                             _Float16* __restrict__ fprep, float* __restrict__ fconst) {
    if (blockIdx.x == 108) {
        int o = threadIdx.x;
        if (o < POUT) {
            float s = bias[o];
            for (int c = 0; c < PIN; ++c) s += f[(size_t)(o * PIN + c) * 100];
            fconst[o] = s;
        }
        return;
    }
    int tid = blockIdx.x * 256 + threadIdx.x;   // 0..27647 = 54*64*8
    int feat = tid >> 9;                        // /512
    int rem = tid & 511;
    int o = rem >> 3;
    int cg = rem & 7;                           // c-group: c = cg*8 + jj
    int k = KT[feat], l = LT[feat];

    half8 chunk;
    #pragma unroll
    for (int jj = 0; jj < 8; ++jj) {
        int c = cg * 8 + jj;
        const float* fc = f + (size_t)(o * PIN + c) * 100;
        float v;
        if (k == 0)      v = fc[l] + fc[l * 10];
        else if (k == l) v = fc[k * 10 + k];
        else             v = fc[k * 10 + l] + fc[l * 10 + k];
        chunk[jj] = (_Float16)v;
    }
    int lane = (o & 31) + 32 * (cg & 1);
    size_t byte = (size_t)feat * 8192 + (cg >> 1) * 2048 + (o >> 5) * 1024 + lane * 16;
    *(half8*)((char*)fprep + byte) = chunk;
}

// ---------------- main MFMA kernel ----------------
// grid 512 = b(8) x hrow(64), XCD-swizzled; block 512 thr = 8 waves =
// 2 m-tiles (32 px) x 4 kc-quarters (K=16). MFMA 32x32x16_f16.
// Barrier-free main loop: each wave streams its B fragments from global
// (fragment-ordered, fully coalesced) through a depth-4 register ring.
__global__ __launch_bounds__(512, 4) void poly2d_mfma(
    const float* __restrict__ x, const _Float16* __restrict__ fprep,
    const float* __restrict__ fconst, float* __restrict__ out)
{
    __shared__ __align__(16) char smx[25344];  // x tile [3][66][8cg swz][16B]; reused as os[64][65] f32

    const int t = threadIdx.x;
    const int lane = t & 63;
    const int wid = t >> 6;            // 0..7
    // XCD-bijective swizzle (512 % 8 == 0)
    const int bid = (blockIdx.x & 7) * 64 + (blockIdx.x >> 3);
    const int b = bid >> 6;
    const int hrow = bid & 63;

    // ---- stage x tile (rows hrow-1..hrow+1, wl 0..65, 64 c) as swizzled fp16 ----
    {
        const int w = t & 63;
        const int wl = w + 1;
        #pragma unroll
        for (int h = 0; h < 3; ++h) {
            int h_in = hrow - 1 + h;
            bool hok = ((unsigned)h_in < HH);
            #pragma unroll
            for (int cc = 0; cc < 2; ++cc) {
                int c = wid * 8 + cc * 4;  // channels c..c+3
                float v0 = 0.f, v1 = 0.f, v2 = 0.f, v3 = 0.f;
                if (hok) {
                    const float* gx = x + (((size_t)b * PIN + c) * HH + h_in) * WW + w;
                    v0 = gx[0]; v1 = gx[4096]; v2 = gx[8192]; v3 = gx[12288];
                }
                half4 pk = {(_Float16)v0, (_Float16)v1, (_Float16)v2, (_Float16)v3};
                int byte = ((h * 66 + wl) * 8 + ((c >> 3) ^ (wl & 7))) * 16 + (c & 7) * 2;
                *(half4*)(smx + byte) = pk;
            }
        }
        if (t < 48) { // w halo: wl=0 and wl=65 out of image -> zero
            int h = t >> 4, side = (t >> 3) & 1, cg = t & 7;
            int wl2 = side ? 65 : 0;
            int byte = ((h * 66 + wl2) * 8 + (cg ^ (wl2 & 7))) * 16;
            f32x4 z = {0.f, 0.f, 0.f, 0.f};
            *(f32x4*)(smx + byte) = z;
        }
    }
    __syncthreads();

    const int kc = wid >> 1;           // 0..3 channel quarter
    const int mwid = wid & 1;          // m-tile (w-half)
    const int wbase = mwid * 32;
    const int l31 = lane & 31;
    const int lhi = lane >> 5;         // 0/1

    // ---- load 9 shift panels (A-frag: row=lane&31 -> pixel, k=(lane>>5)*8+j) ----
    half8 xp[9];
    #pragma unroll
    for (int p = 1; p <= 9; ++p) {
        const int dh = (p - 1) / 3 - 1, dw = (p - 1) % 3 - 1;
        int wl = wbase + l31 + dw + 1;
        int hidx = dh + 1;
        int cgl = kc * 2 + lhi;
        int byte = ((hidx * 66 + wl) * 8 + (cgl ^ (wl & 7))) * 16;
        xp[p - 1] = *(const half8*)(smx + byte);
    }
    __syncthreads(); // all xp reads done before the os-write epilogue may start

    // ---- barrier-free streaming loop: coalesced B frags, depth-4 reg ring ----
    // fragment order: b0 @ f*8192 + kc*2048 + lane*16 ; b1 @ +1024
    const char* fbase = (const char*)fprep + (kc << 11) + (lane << 4);

    half8 Bb[4][2];
    #pragma unroll
    for (int s = 0; s < 3; ++s) {
        Bb[s][0] = *(const half8*)(fbase + (size_t)s * 8192);
        Bb[s][1] = *(const half8*)(fbase + (size_t)s * 8192 + 1024);
    }

    f32x16 acc0 = {}, acc1 = {};

    #pragma unroll
    for (int f = 0; f < NFEAT; ++f) {
        if (f + 3 < NFEAT) {
            Bb[(f + 3) & 3][0] = *(const half8*)(fbase + (size_t)(f + 3) * 8192);
            Bb[(f + 3) & 3][1] = *(const half8*)(fbase + (size_t)(f + 3) * 8192 + 1024);
        }
        const int k = KT[f], l = LT[f];
        half8 a = (k == 0) ? xp[l - 1] : xp[k - 1] * xp[l - 1];
        acc0 = __builtin_amdgcn_mfma_f32_32x32x16_f16(a, Bb[f & 3][0], acc0, 0, 0, 0);
        acc1 = __builtin_amdgcn_mfma_f32_32x32x16_f16(a, Bb[f & 3][1], acc1, 0, 0, 0);
    }

    __syncthreads(); // loop done; x-region free for output staging
    float* os = (float*)smx; // [64 px][65]

    // reduce 4 kc partials (C/D: col=lane&31 (+nb*32), row=(r&3)+8*(r>>2)+4*lhi)
    #pragma unroll
    for (int pass = 0; pass < 4; ++pass) {
        if (kc == pass) {
            #pragma unroll
            for (int nb = 0; nb < 2; ++nb) {
                #pragma unroll
                for (int r = 0; r < 16; ++r) {
                    int row = (r & 3) + 8 * (r >> 2) + 4 * lhi;
                    int m = mwid * 32 + row;
                    int col = l31 + nb * 32;
                    float v = nb ? acc1[r] : acc0[r];
                    if (pass == 0) os[m * 65 + col] = v;
                    else           os[m * 65 + col] += v;
                }
            }
        }
        __syncthreads();
    }

    { // coalesced store: lanes sweep w
        const int w = t & 63;
        #pragma unroll
        for (int oo = 0; oo < 8; ++oo) {
            int o = wid * 8 + oo;
            float val = os[w * 65 + o] + fconst[o];
            out[(((size_t)b * POUT + o) * HH + hrow) * WW + w] = val;
        }
    }
}

// ---------------- fp32 fallback, used only if ws too small ----------------
__global__ __launch_bounds__(256) void poly2d_fp32(
    const float* __restrict__ x, const float* __restrict__ f,
    const float* __restrict__ bias, float* __restrict__ out)
{
    const int t = threadIdx.x;
    const int wo = t & 63;
    const int ho = (blockIdx.x & 15) * 4 + (t >> 6);
    const int o = (blockIdx.x >> 4) & 63;
    const int b = blockIdx.x >> 10;

    float acc = bias[o];
    const float* xb = x + (size_t)b * PIN * HH * WW;
    const float* fo = f + (size_t)o * PIN * 100;
    for (int c = 0; c < PIN; ++c) {
        const float* xc = xb + (size_t)c * HH * WW;
        float s[10];
        s[0] = 1.0f;
        #pragma unroll
        for (int kh = 0; kh < 3; ++kh) {
            int h = ho - 1 + kh;
            bool hok = ((unsigned)h < HH);
            #pragma unroll
            for (int kw = 0; kw < 3; ++kw) {
                int w = wo - 1 + kw;
                s[1 + kh * 3 + kw] = (hok && (unsigned)w < WW) ? xc[h * WW + w] : 0.0f;
            }
        }
        const float* fc = fo + c * 100;
        #pragma unroll
        for (int i = 0; i < 10; ++i) {
            float wsum = 0.0f;
            #pragma unroll
            for (int j = 0; j < 10; ++j) wsum = fmaf(fc[i * 10 + j], s[j], wsum);
            acc = fmaf(wsum, s[i], acc);
        }
    }
    out[(((size_t)b * POUT + o) * HH + ho) * WW + wo] = acc;
}

extern "C" void kernel_launch(void* const* d_in, const int* in_sizes, int n_in,
                              void* d_out, int out_size, void* d_ws, size_t ws_size,
                              hipStream_t stream) {
    const float* x    = (const float*)d_in[0];
    const float* filt = (const float*)d_in[1];
    const float* bias = (const float*)d_in[2];
    float* out = (float*)d_out;

    const size_t FPREP_BYTES = (size_t)NFEAT * POUT * PIN * 2; // 442368
    if (ws_size < FPREP_BYTES + 256) {
        poly2d_fp32<<<dim3(8 * 64 * 16), dim3(256), 0, stream>>>(x, filt, bias, out);
        return;
    }
    _Float16* fprep = (_Float16*)d_ws;
    float* fconst = (float*)((char*)d_ws + FPREP_BYTES);

    prep_filters<<<dim3(109), dim3(256), 0, stream>>>(filt, bias, fprep, fconst);
    poly2d_mfma<<<dim3(512), dim3(512), 0, stream>>>(x, fprep, fconst, out);
}